// Round 3
// baseline (487.541 us; speedup 1.0000x reference)
//
#include <hip/hip_runtime.h>
#include <stdint.h>

#define N 8192
#define IN_F 512
#define OUT_F 128
#define NCLS 10
#define ALPHA 0.2f

typedef float f32x4 __attribute__((ext_vector_type(4)));
typedef int   i32x4 __attribute__((ext_vector_type(4)));
typedef short s16x4 __attribute__((ext_vector_type(4)));
typedef short s16x8 __attribute__((ext_vector_type(8)));

__device__ __forceinline__ short f2bf(float x) {
    unsigned u = __builtin_bit_cast(unsigned, x);
    u = (u + 0x7FFFu + ((u >> 16) & 1u)) >> 16;  // RNE
    return (short)u;
}
__device__ __forceinline__ float bf2f(short s) {
    unsigned u = ((unsigned)(unsigned short)s) << 16;
    return __builtin_bit_cast(float, u);
}

// ---------------------------------------------------------------------------
// Kernel 0: split W [512][128] fp32 -> bf16 hi/lo in fragment-blocked layout:
// idx(col,k) = (k>>5)*(128*32) + col*32 + (k&31)
// ---------------------------------------------------------------------------
__global__ void split_w_kernel(const float* __restrict__ W,
                               short* __restrict__ WThi, short* __restrict__ WTlo) {
    int idx = blockIdx.x * 256 + threadIdx.x;       // 512*128 = 65536
    int k = idx >> 7, col = idx & 127;
    float x = W[idx];                               // row-major [k][col]
    short hi = f2bf(x);
    short lo = f2bf(x - bf2f(hi));
    size_t a = (size_t)(k >> 5) * (128 * 32) + (size_t)col * 32 + (k & 31);
    WThi[a] = hi;
    WTlo[a] = lo;
}

// ---------------------------------------------------------------------------
// Kernel 1: Wh = h@W via split-bf16 MFMA (3 products). Writes Wh1/Wh2 (fp32)
// and WhT bf16 fragment-blocked [(j>>5)][col][j&31].
// 512 blocks x 256 threads, 16 rows/block.
// ---------------------------------------------------------------------------
#define WH_ROWS 16
#define WH_STR 520   // 512 + 8 shorts pad: frag reads land 2-way (free)

__global__ __launch_bounds__(256, 2)
void wh_kernel(const float* __restrict__ h, const short* __restrict__ WThi,
               const short* __restrict__ WTlo, const float* __restrict__ a,
               short* __restrict__ WhT, float* __restrict__ Wh1,
               float* __restrict__ Wh2) {
    __shared__ __align__(16) short Ahi[WH_ROWS][WH_STR];
    __shared__ __align__(16) short Alo[WH_ROWS][WH_STR];
    __shared__ __align__(16) float whs[WH_ROWS][OUT_F + 4];

    const int t = threadIdx.x;
    const int r0 = blockIdx.x * WH_ROWS;

    {   // stage h tile [16][512] as bf16 hi/lo (coalesced 32B/lane reads)
        int row = t >> 4, c4 = t & 15;
        const float* hrow = h + (size_t)(r0 + row) * IN_F;
        #pragma unroll
        for (int jj = 0; jj < 4; ++jj) {
            int k0 = c4 * 8 + jj * 128;
            f32x4 x0 = *(const f32x4*)(hrow + k0);
            f32x4 x1 = *(const f32x4*)(hrow + k0 + 4);
            s16x8 hi, lo;
            #pragma unroll
            for (int e = 0; e < 4; ++e) {
                short h0 = f2bf(x0[e]); hi[e] = h0; lo[e] = f2bf(x0[e] - bf2f(h0));
                short h1 = f2bf(x1[e]); hi[4 + e] = h1; lo[4 + e] = f2bf(x1[e] - bf2f(h1));
            }
            *(s16x8*)&Ahi[row][k0] = hi;
            *(s16x8*)&Alo[row][k0] = lo;
        }
    }
    __syncthreads();

    const int lane = t & 63, w = t >> 6;
    const int q = lane >> 4, ln16 = lane & 15;
    f32x4 acc[2] = {};
    #pragma unroll
    for (int kc = 0; kc < IN_F / 32; ++kc) {
        s16x8 ahi = *(const s16x8*)&Ahi[ln16][kc * 32 + q * 8];
        s16x8 alo = *(const s16x8*)&Alo[ln16][kc * 32 + q * 8];
        #pragma unroll
        for (int nt = 0; nt < 2; ++nt) {
            int col = w * 32 + nt * 16 + ln16;
            size_t boff = (size_t)kc * 4096 + (size_t)col * 32 + q * 8;
            s16x8 bhi = *(const s16x8*)(WThi + boff);
            s16x8 blo = *(const s16x8*)(WTlo + boff);
            acc[nt] = __builtin_amdgcn_mfma_f32_16x16x32_bf16(ahi, bhi, acc[nt], 0, 0, 0);
            acc[nt] = __builtin_amdgcn_mfma_f32_16x16x32_bf16(ahi, blo, acc[nt], 0, 0, 0);
            acc[nt] = __builtin_amdgcn_mfma_f32_16x16x32_bf16(alo, bhi, acc[nt], 0, 0, 0);
        }
    }
    #pragma unroll
    for (int nt = 0; nt < 2; ++nt)
        #pragma unroll
        for (int reg = 0; reg < 4; ++reg)
            whs[q * 4 + reg][w * 32 + nt * 16 + ln16] = acc[nt][reg];
    __syncthreads();

    // Wh1/Wh2: 16 rows, 8 threads per row
    if (t < 128) {
        int r = t >> 3, s = t & 7;
        float s1 = 0.f, s2 = 0.f;
        #pragma unroll
        for (int cc = 0; cc < 16; ++cc) {
            int c = s * 16 + cc;
            float v = whs[r][c];
            s1 = fmaf(v, a[c], s1);
            s2 = fmaf(v, a[OUT_F + c], s2);
        }
        s1 += __shfl_xor(s1, 1); s1 += __shfl_xor(s1, 2); s1 += __shfl_xor(s1, 4);
        s2 += __shfl_xor(s2, 1); s2 += __shfl_xor(s2, 2); s2 += __shfl_xor(s2, 4);
        if (s == 0) { Wh1[r0 + r] = s1; Wh2[r0 + r] = s2; }
    }

    // WhT bf16, fragment-blocked: idx = (j>>5)*4096 + col*32 + (j&31)
    {
        int c = t >> 1, h8 = t & 1;
        s16x8 pack;
        #pragma unroll
        for (int rr = 0; rr < 8; ++rr) pack[rr] = f2bf(whs[h8 * 8 + rr][c]);
        size_t addr = (size_t)(r0 >> 5) * 4096 + (size_t)c * 32 + (r0 & 16) + h8 * 8;
        *(s16x8*)(WhT + addr) = pack;
    }
}

// ---------------------------------------------------------------------------
// Kernel 2 (v3): barrier-free, LDS-free attention. Each lane computes its
// MFMA A-fragment (8 consecutive j-scores of ONE row) directly in registers:
// lane (q,ln16) of wave w owns row i0+w*16+ln16, k-slice q*8..q*8+7 of each
// 32-j step. dist is read exactly once, fused, at streaming rate (128 B/row
// per kc, 256 sequential row-streams per CU). No mask kernel, no LDS, no
// __syncthreads. 8 MFMAs/kc (all 128 out-cols per wave), acc[8] f32x4.
// grid = 128 * SPLIT blocks, 256 threads (4 waves), 64 rows/block.
// ---------------------------------------------------------------------------
#define BM2 64

__global__ __launch_bounds__(256, 4)
void attn_kernel(const int* __restrict__ dist, const short* __restrict__ WhT,
                 const float* __restrict__ Wh1v, const float* __restrict__ Wh2v,
                 float* __restrict__ acc_part, float* __restrict__ l_part,
                 int nkc, int jspan) {
    const int t = threadIdx.x;
    const int it = blockIdx.x & 127;          // N/BM2 = 128 i-tiles
    const int sp = blockIdx.x >> 7;
    const int i0 = it * BM2;
    const int w = t >> 6, lane = t & 63;
    const int q = lane >> 4, ln16 = lane & 15;
    const int row = i0 + w * 16 + ln16;
    const int j0 = sp * jspan;

    const int*   __restrict__ dp = dist + (size_t)row * N + j0 + q * 8;
    const float* __restrict__ wp = Wh2v + j0 + q * 8;
    const float wh1 = Wh1v[row];
    const short* __restrict__ wb0 = WhT + ((size_t)(j0 >> 5)) * 4096 + ln16 * 32 + q * 8;

    f32x4 acc[8] = {};
    float l_acc = 0.f;

    // 2-deep register prefetch on the HBM stream (dist) and Wh2
    i32x4 dA = *(const i32x4*)(dp);
    i32x4 dB = *(const i32x4*)(dp + 4);
    f32x4 wA = *(const f32x4*)(wp);
    f32x4 wB = *(const f32x4*)(wp + 4);

    for (int kc = 0; kc < nkc; ++kc) {
        i32x4 dA2, dB2; f32x4 wA2, wB2;
        const bool more = (kc + 1) < nkc;
        if (more) {
            dA2 = *(const i32x4*)(dp + (kc + 1) * 32);
            dB2 = *(const i32x4*)(dp + (kc + 1) * 32 + 4);
            wA2 = *(const f32x4*)(wp + (kc + 1) * 32);
            wB2 = *(const f32x4*)(wp + (kc + 1) * 32 + 4);
        }
        s16x8 af;
        #pragma unroll
        for (int e = 0; e < 4; ++e) {
            float sv = wh1 + wA[e];
            float lr = fmaxf(sv, ALPHA * sv);
            float pv = (dA[e] > 0) ? __expf(lr) : 0.f;
            l_acc += pv;
            af[e] = f2bf(pv);
        }
        #pragma unroll
        for (int e = 0; e < 4; ++e) {
            float sv = wh1 + wB[e];
            float lr = fmaxf(sv, ALPHA * sv);
            float pv = (dB[e] > 0) ? __expf(lr) : 0.f;
            l_acc += pv;
            af[4 + e] = f2bf(pv);
        }
        const short* wb = wb0 + (size_t)kc * 4096;
        #pragma unroll
        for (int nt = 0; nt < 8; ++nt) {
            s16x8 b = *(const s16x8*)(wb + nt * 512);   // col=nt*16+ln16, 16B/lane
            acc[nt] = __builtin_amdgcn_mfma_f32_16x16x32_bf16(af, b, acc[nt], 0, 0, 0);
        }
        if (more) { dA = dA2; dB = dB2; wA = wA2; wB = wB2; }
    }

    // row sums: lane (q,ln16) holds a q-partial of row's sum; sum across q
    l_acc += __shfl_xor(l_acc, 16);
    l_acc += __shfl_xor(l_acc, 32);
    if (lane < 16) l_part[(size_t)sp * N + row] = l_acc;

    // C/D: col = nt*16+ln16, row-within-16 = q*4+reg
    float* ap = acc_part + (size_t)sp * N * OUT_F + (size_t)(i0 + w * 16) * OUT_F;
    #pragma unroll
    for (int reg = 0; reg < 4; ++reg) {
        int rr = q * 4 + reg;
        #pragma unroll
        for (int nt = 0; nt < 8; ++nt)
            ap[(size_t)rr * OUT_F + nt * 16 + ln16] = acc[nt][reg];
    }
}

// ---------------------------------------------------------------------------
// Kernel 3: reduce partials, softmax-divide, elu, classifier.
// 512 blocks x 256 threads, 16 rows/block.
// ---------------------------------------------------------------------------
__global__ __launch_bounds__(256, 4)
void reduce_kernel(const float* __restrict__ acc_part, const float* __restrict__ l_part,
                   const float* __restrict__ Wc, const float* __restrict__ bcv,
                   float* __restrict__ out, int split) {
    __shared__ __align__(16) float hu[16][OUT_F + 4];
    const int t = threadIdx.x;
    const int i0 = blockIdx.x * 16;
    const int row = t >> 4, cg = t & 15;

    f32x4 v0 = {0.f, 0.f, 0.f, 0.f}, v1 = {0.f, 0.f, 0.f, 0.f};
    float l = 0.f;
    for (int s = 0; s < split; ++s) {
        const float* ap = acc_part + (size_t)s * N * OUT_F + (size_t)(i0 + row) * OUT_F + cg * 8;
        v0 += *(const f32x4*)ap;
        v1 += *(const f32x4*)(ap + 4);
        l += l_part[(size_t)s * N + i0 + row];
    }
    float inv = 1.f / l;
    #pragma unroll
    for (int e = 0; e < 4; ++e) {
        float x0 = v0[e] * inv; x0 = x0 > 0.f ? x0 : (__expf(x0) - 1.f);
        float x1 = v1[e] * inv; x1 = x1 > 0.f ? x1 : (__expf(x1) - 1.f);
        hu[row][cg * 8 + e] = x0;
        hu[row][cg * 8 + 4 + e] = x1;
    }
    __syncthreads();

    if (t < 16 * NCLS) {
        int rr = t / NCLS, cls = t - rr * NCLS;
        const f32x4* hurow = (const f32x4*)&hu[rr][0];
        const f32x4* wcrow = (const f32x4*)(Wc + cls * OUT_F);
        float sum = bcv[cls];
        #pragma unroll 8
        for (int c4 = 0; c4 < OUT_F / 4; ++c4) {
            f32x4 hv = hurow[c4];
            f32x4 wv = wcrow[c4];
            sum += hv[0] * wv[0] + hv[1] * wv[1] + hv[2] * wv[2] + hv[3] * wv[3];
        }
        out[(size_t)(i0 + rr) * NCLS + cls] = sum;
    }
}

// ---------------------------------------------------------------------------
extern "C" void kernel_launch(void* const* d_in, const int* in_sizes, int n_in,
                              void* d_out, int out_size, void* d_ws, size_t ws_size,
                              hipStream_t stream) {
    const float* h    = (const float*)d_in[0];
    const int*   dist = (const int*)d_in[1];
    const float* W    = (const float*)d_in[2];
    const float* a    = (const float*)d_in[3];
    const float* Wc   = (const float*)d_in[4];
    const float* bc   = (const float*)d_in[5];
    float* out = (float*)d_out;

    char* ws = (char*)d_ws;
    size_t off = 0;
    short* WhT  = (short*)(ws + off); off += (size_t)OUT_F * N * 2;     // 2 MB
    short* WThi = (short*)(ws + off); off += (size_t)IN_F * OUT_F * 2;  // 128 KB
    short* WTlo = (short*)(ws + off); off += (size_t)IN_F * OUT_F * 2;  // 128 KB
    float* Wh1  = (float*)(ws + off); off += (size_t)N * 4;
    float* Wh2  = (float*)(ws + off); off += (size_t)N * 4;

    size_t per_split = (size_t)N * OUT_F * 4 + (size_t)N * 4;
    int split = 8;
    while (split > 1 && off + (size_t)split * per_split > ws_size) split >>= 1;
    float* acc_part = (float*)(ws + off); off += (size_t)split * N * OUT_F * 4;
    float* l_part   = (float*)(ws + off);

    hipLaunchKernelGGL(split_w_kernel, dim3(256), dim3(256), 0, stream, W, WThi, WTlo);
    hipLaunchKernelGGL(wh_kernel, dim3(N / WH_ROWS), dim3(256), 0, stream,
                       h, WThi, WTlo, a, WhT, Wh1, Wh2);
    hipLaunchKernelGGL(attn_kernel, dim3(128 * split), dim3(256), 0, stream,
                       dist, WhT, Wh1, Wh2, acc_part, l_part,
                       N / (32 * split), N / split);
    hipLaunchKernelGGL(reduce_kernel, dim3(N / 16), dim3(256), 0, stream,
                       acc_part, l_part, Wc, bc, out, split);
}

// Round 4
// 479.867 us; speedup vs baseline: 1.0160x; 1.0160x over previous
//
#include <hip/hip_runtime.h>
#include <stdint.h>

#define N 8192
#define IN_F 512
#define OUT_F 128
#define NCLS 10
#define ALPHA 0.2f

typedef float f32x4 __attribute__((ext_vector_type(4)));
typedef int   i32x4 __attribute__((ext_vector_type(4)));
typedef short s16x4 __attribute__((ext_vector_type(4)));
typedef short s16x8 __attribute__((ext_vector_type(8)));

__device__ __forceinline__ short f2bf(float x) {
    unsigned u = __builtin_bit_cast(unsigned, x);
    u = (u + 0x7FFFu + ((u >> 16) & 1u)) >> 16;  // RNE
    return (short)u;
}
__device__ __forceinline__ float bf2f(short s) {
    unsigned u = ((unsigned)(unsigned short)s) << 16;
    return __builtin_bit_cast(float, u);
}

// ---------------------------------------------------------------------------
// Kernel M: dist (int32 0/1, 268 MB) -> 1-bit adjacency mask (8 MB).
// Pure streaming: 128 B contiguous read + 4 B write per thread, no dependent
// chains -> saturates HBM (~44 us measured r2). ONLY reader of dist.
// Word w covers row i = w/256, j in [(w%256)*32, +32); bit = j%32.
// ---------------------------------------------------------------------------
__global__ __launch_bounds__(256, 8)
void mask_kernel(const int* __restrict__ dist, unsigned* __restrict__ mask) {
    size_t w = (size_t)blockIdx.x * 256 + threadIdx.x;   // 8192*256 words
    const int* p = dist + w * 32;
    unsigned b = 0;
    #pragma unroll
    for (int u = 0; u < 8; ++u) {
        i32x4 v = *(const i32x4*)(p + u * 4);
        #pragma unroll
        for (int e = 0; e < 4; ++e) b |= (v[e] > 0 ? 1u : 0u) << (u * 4 + e);
    }
    mask[w] = b;
}

// ---------------------------------------------------------------------------
// Kernel 0: split W [512][128] fp32 -> bf16 hi/lo in fragment-blocked layout:
// idx(col,k) = (k>>5)*(128*32) + col*32 + (k&31)
// ---------------------------------------------------------------------------
__global__ void split_w_kernel(const float* __restrict__ W,
                               short* __restrict__ WThi, short* __restrict__ WTlo) {
    int idx = blockIdx.x * 256 + threadIdx.x;       // 512*128 = 65536
    int k = idx >> 7, col = idx & 127;
    float x = W[idx];                               // row-major [k][col]
    short hi = f2bf(x);
    short lo = f2bf(x - bf2f(hi));
    size_t a = (size_t)(k >> 5) * (128 * 32) + (size_t)col * 32 + (k & 31);
    WThi[a] = hi;
    WTlo[a] = lo;
}

// ---------------------------------------------------------------------------
// Kernel 1: Wh = h@W via split-bf16 MFMA (3 products). Writes Wh1/Wh2 (fp32)
// and WhT bf16 fragment-blocked [(j>>5)][col][j&31].
// 512 blocks x 256 threads, 16 rows/block.
// ---------------------------------------------------------------------------
#define WH_ROWS 16
#define WH_STR 520   // 512 + 8 shorts pad: frag reads land 2-way (free)

__global__ __launch_bounds__(256, 2)
void wh_kernel(const float* __restrict__ h, const short* __restrict__ WThi,
               const short* __restrict__ WTlo, const float* __restrict__ a,
               short* __restrict__ WhT, float* __restrict__ Wh1,
               float* __restrict__ Wh2) {
    __shared__ __align__(16) short Ahi[WH_ROWS][WH_STR];
    __shared__ __align__(16) short Alo[WH_ROWS][WH_STR];
    __shared__ __align__(16) float whs[WH_ROWS][OUT_F + 4];

    const int t = threadIdx.x;
    const int r0 = blockIdx.x * WH_ROWS;

    {   // stage h tile [16][512] as bf16 hi/lo (coalesced 32B/lane reads)
        int row = t >> 4, c4 = t & 15;
        const float* hrow = h + (size_t)(r0 + row) * IN_F;
        #pragma unroll
        for (int jj = 0; jj < 4; ++jj) {
            int k0 = c4 * 8 + jj * 128;
            f32x4 x0 = *(const f32x4*)(hrow + k0);
            f32x4 x1 = *(const f32x4*)(hrow + k0 + 4);
            s16x8 hi, lo;
            #pragma unroll
            for (int e = 0; e < 4; ++e) {
                short h0 = f2bf(x0[e]); hi[e] = h0; lo[e] = f2bf(x0[e] - bf2f(h0));
                short h1 = f2bf(x1[e]); hi[4 + e] = h1; lo[4 + e] = f2bf(x1[e] - bf2f(h1));
            }
            *(s16x8*)&Ahi[row][k0] = hi;
            *(s16x8*)&Alo[row][k0] = lo;
        }
    }
    __syncthreads();

    const int lane = t & 63, w = t >> 6;
    const int q = lane >> 4, ln16 = lane & 15;
    f32x4 acc[2] = {};
    #pragma unroll
    for (int kc = 0; kc < IN_F / 32; ++kc) {
        s16x8 ahi = *(const s16x8*)&Ahi[ln16][kc * 32 + q * 8];
        s16x8 alo = *(const s16x8*)&Alo[ln16][kc * 32 + q * 8];
        #pragma unroll
        for (int nt = 0; nt < 2; ++nt) {
            int col = w * 32 + nt * 16 + ln16;
            size_t boff = (size_t)kc * 4096 + (size_t)col * 32 + q * 8;
            s16x8 bhi = *(const s16x8*)(WThi + boff);
            s16x8 blo = *(const s16x8*)(WTlo + boff);
            acc[nt] = __builtin_amdgcn_mfma_f32_16x16x32_bf16(ahi, bhi, acc[nt], 0, 0, 0);
            acc[nt] = __builtin_amdgcn_mfma_f32_16x16x32_bf16(ahi, blo, acc[nt], 0, 0, 0);
            acc[nt] = __builtin_amdgcn_mfma_f32_16x16x32_bf16(alo, bhi, acc[nt], 0, 0, 0);
        }
    }
    #pragma unroll
    for (int nt = 0; nt < 2; ++nt)
        #pragma unroll
        for (int reg = 0; reg < 4; ++reg)
            whs[q * 4 + reg][w * 32 + nt * 16 + ln16] = acc[nt][reg];
    __syncthreads();

    // Wh1/Wh2: 16 rows, 8 threads per row
    if (t < 128) {
        int r = t >> 3, s = t & 7;
        float s1 = 0.f, s2 = 0.f;
        #pragma unroll
        for (int cc = 0; cc < 16; ++cc) {
            int c = s * 16 + cc;
            float v = whs[r][c];
            s1 = fmaf(v, a[c], s1);
            s2 = fmaf(v, a[OUT_F + c], s2);
        }
        s1 += __shfl_xor(s1, 1); s1 += __shfl_xor(s1, 2); s1 += __shfl_xor(s1, 4);
        s2 += __shfl_xor(s2, 1); s2 += __shfl_xor(s2, 2); s2 += __shfl_xor(s2, 4);
        if (s == 0) { Wh1[r0 + r] = s1; Wh2[r0 + r] = s2; }
    }

    // WhT bf16, fragment-blocked: idx = (j>>5)*4096 + col*32 + (j&31)
    {
        int c = t >> 1, h8 = t & 1;
        s16x8 pack;
        #pragma unroll
        for (int rr = 0; rr < 8; ++rr) pack[rr] = f2bf(whs[h8 * 8 + rr][c]);
        size_t addr = (size_t)(r0 >> 5) * 4096 + (size_t)c * 32 + (r0 & 16) + h8 * 8;
        *(s16x8*)(WhT + addr) = pack;
    }
}

// ---------------------------------------------------------------------------
// Kernel 2 (v4): barrier-free, LDS-free attention fed by the bitmask.
// Lane (q,ln16) of wave w owns row i0+w*16+ln16 and builds its MFMA
// A-fragment (8 consecutive j-scores) in registers. Per-iteration loads:
// 1 mask dword (broadcast across q -> L1), 32 B Wh2 (shared -> L1),
// 8x16 B WhT B-frags (L1 after first wave). No HBM in the hot loop.
// grid = 128 * SPLIT blocks, 256 threads (4 waves), 64 rows/block.
// ---------------------------------------------------------------------------
#define BM2 64

__global__ __launch_bounds__(256, 4)
void attn_kernel(const unsigned* __restrict__ mask, const short* __restrict__ WhT,
                 const float* __restrict__ Wh1v, const float* __restrict__ Wh2v,
                 float* __restrict__ acc_part, float* __restrict__ l_part,
                 int nkc, int jspan) {
    const int t = threadIdx.x;
    const int it = blockIdx.x & 127;          // N/BM2 = 128 i-tiles
    const int sp = blockIdx.x >> 7;
    const int i0 = it * BM2;
    const int w = t >> 6, lane = t & 63;
    const int q = lane >> 4, ln16 = lane & 15;
    const int row = i0 + w * 16 + ln16;
    const int j0 = sp * jspan;

    const unsigned* __restrict__ mp = mask + (size_t)row * (N / 32) + (j0 >> 5);
    const float* __restrict__ wp = Wh2v + j0 + q * 8;
    const float wh1 = Wh1v[row];
    const short* __restrict__ wb0 = WhT + ((size_t)(j0 >> 5)) * 4096 + ln16 * 32 + q * 8;

    f32x4 acc[8] = {};
    float l_acc = 0.f;

    // 1-deep register prefetch (all L1/L2-resident)
    unsigned mw = mp[0];
    f32x4 wA = *(const f32x4*)(wp);
    f32x4 wB = *(const f32x4*)(wp + 4);

    for (int kc = 0; kc < nkc; ++kc) {
        unsigned mw2 = 0; f32x4 wA2, wB2;
        const bool more = (kc + 1) < nkc;
        if (more) {
            mw2 = mp[kc + 1];
            wA2 = *(const f32x4*)(wp + (kc + 1) * 32);
            wB2 = *(const f32x4*)(wp + (kc + 1) * 32 + 4);
        }
        const unsigned byte = mw >> (q * 8);   // bits [q*8, q*8+8) of 32-j window
        s16x8 af;
        #pragma unroll
        for (int e = 0; e < 4; ++e) {
            float sv = wh1 + wA[e];
            float lr = fmaxf(sv, ALPHA * sv);
            float pv = (byte & (1u << e)) ? __expf(lr) : 0.f;
            l_acc += pv;
            af[e] = f2bf(pv);
        }
        #pragma unroll
        for (int e = 0; e < 4; ++e) {
            float sv = wh1 + wB[e];
            float lr = fmaxf(sv, ALPHA * sv);
            float pv = (byte & (1u << (4 + e))) ? __expf(lr) : 0.f;
            l_acc += pv;
            af[4 + e] = f2bf(pv);
        }
        const short* wb = wb0 + (size_t)kc * 4096;
        #pragma unroll
        for (int nt = 0; nt < 8; ++nt) {
            s16x8 b = *(const s16x8*)(wb + nt * 512);   // col=nt*16+ln16, 16B/lane
            acc[nt] = __builtin_amdgcn_mfma_f32_16x16x32_bf16(af, b, acc[nt], 0, 0, 0);
        }
        if (more) { mw = mw2; wA = wA2; wB = wB2; }
    }

    // row sums: reduce the q-partials of each row
    l_acc += __shfl_xor(l_acc, 16);
    l_acc += __shfl_xor(l_acc, 32);
    if (lane < 16) l_part[(size_t)sp * N + row] = l_acc;

    // C/D: col = nt*16+ln16, row-within-16 = q*4+reg
    float* ap = acc_part + (size_t)sp * N * OUT_F + (size_t)(i0 + w * 16) * OUT_F;
    #pragma unroll
    for (int reg = 0; reg < 4; ++reg) {
        int rr = q * 4 + reg;
        #pragma unroll
        for (int nt = 0; nt < 8; ++nt)
            ap[(size_t)rr * OUT_F + nt * 16 + ln16] = acc[nt][reg];
    }
}

// ---------------------------------------------------------------------------
// Kernel 3: reduce partials, softmax-divide, elu, classifier.
// 512 blocks x 256 threads, 16 rows/block.
// ---------------------------------------------------------------------------
__global__ __launch_bounds__(256, 4)
void reduce_kernel(const float* __restrict__ acc_part, const float* __restrict__ l_part,
                   const float* __restrict__ Wc, const float* __restrict__ bcv,
                   float* __restrict__ out, int split) {
    __shared__ __align__(16) float hu[16][OUT_F + 4];
    const int t = threadIdx.x;
    const int i0 = blockIdx.x * 16;
    const int row = t >> 4, cg = t & 15;

    f32x4 v0 = {0.f, 0.f, 0.f, 0.f}, v1 = {0.f, 0.f, 0.f, 0.f};
    float l = 0.f;
    for (int s = 0; s < split; ++s) {
        const float* ap = acc_part + (size_t)s * N * OUT_F + (size_t)(i0 + row) * OUT_F + cg * 8;
        v0 += *(const f32x4*)ap;
        v1 += *(const f32x4*)(ap + 4);
        l += l_part[(size_t)s * N + i0 + row];
    }
    float inv = 1.f / l;
    #pragma unroll
    for (int e = 0; e < 4; ++e) {
        float x0 = v0[e] * inv; x0 = x0 > 0.f ? x0 : (__expf(x0) - 1.f);
        float x1 = v1[e] * inv; x1 = x1 > 0.f ? x1 : (__expf(x1) - 1.f);
        hu[row][cg * 8 + e] = x0;
        hu[row][cg * 8 + 4 + e] = x1;
    }
    __syncthreads();

    if (t < 16 * NCLS) {
        int rr = t / NCLS, cls = t - rr * NCLS;
        const f32x4* hurow = (const f32x4*)&hu[rr][0];
        const f32x4* wcrow = (const f32x4*)(Wc + cls * OUT_F);
        float sum = bcv[cls];
        #pragma unroll 8
        for (int c4 = 0; c4 < OUT_F / 4; ++c4) {
            f32x4 hv = hurow[c4];
            f32x4 wv = wcrow[c4];
            sum += hv[0] * wv[0] + hv[1] * wv[1] + hv[2] * wv[2] + hv[3] * wv[3];
        }
        out[(size_t)(i0 + rr) * NCLS + cls] = sum;
    }
}

// ---------------------------------------------------------------------------
extern "C" void kernel_launch(void* const* d_in, const int* in_sizes, int n_in,
                              void* d_out, int out_size, void* d_ws, size_t ws_size,
                              hipStream_t stream) {
    const float* h    = (const float*)d_in[0];
    const int*   dist = (const int*)d_in[1];
    const float* W    = (const float*)d_in[2];
    const float* a    = (const float*)d_in[3];
    const float* Wc   = (const float*)d_in[4];
    const float* bc   = (const float*)d_in[5];
    float* out = (float*)d_out;

    char* ws = (char*)d_ws;
    size_t off = 0;
    short* WhT  = (short*)(ws + off); off += (size_t)OUT_F * N * 2;     // 2 MB
    short* WThi = (short*)(ws + off); off += (size_t)IN_F * OUT_F * 2;  // 128 KB
    short* WTlo = (short*)(ws + off); off += (size_t)IN_F * OUT_F * 2;  // 128 KB
    float* Wh1  = (float*)(ws + off); off += (size_t)N * 4;
    float* Wh2  = (float*)(ws + off); off += (size_t)N * 4;
    unsigned* mask = (unsigned*)(ws + off); off += (size_t)N * (N / 32) * 4; // 8 MB

    size_t per_split = (size_t)N * OUT_F * 4 + (size_t)N * 4;
    int split = 8;
    while (split > 1 && off + (size_t)split * per_split > ws_size) split >>= 1;
    float* acc_part = (float*)(ws + off); off += (size_t)split * N * OUT_F * 4;
    float* l_part   = (float*)(ws + off);

    hipLaunchKernelGGL(mask_kernel, dim3(N * (N / 32) / 256), dim3(256), 0, stream,
                       dist, mask);
    hipLaunchKernelGGL(split_w_kernel, dim3(256), dim3(256), 0, stream, W, WThi, WTlo);
    hipLaunchKernelGGL(wh_kernel, dim3(N / WH_ROWS), dim3(256), 0, stream,
                       h, WThi, WTlo, a, WhT, Wh1, Wh2);
    hipLaunchKernelGGL(attn_kernel, dim3(128 * split), dim3(256), 0, stream,
                       mask, WhT, Wh1, Wh2, acc_part, l_part,
                       N / (32 * split), N / split);
    hipLaunchKernelGGL(reduce_kernel, dim3(N / 16), dim3(256), 0, stream,
                       acc_part, l_part, Wc, bc, out, split);
}

// Round 5
// 472.992 us; speedup vs baseline: 1.0308x; 1.0145x over previous
//
#include <hip/hip_runtime.h>
#include <stdint.h>

#define N 8192
#define IN_F 512
#define OUT_F 128
#define NCLS 10
#define ALPHA 0.2f

typedef float f32x4 __attribute__((ext_vector_type(4)));
typedef int   i32x4 __attribute__((ext_vector_type(4)));
typedef short s16x4 __attribute__((ext_vector_type(4)));
typedef short s16x8 __attribute__((ext_vector_type(8)));

__device__ __forceinline__ short f2bf(float x) {
    unsigned u = __builtin_bit_cast(unsigned, x);
    u = (u + 0x7FFFu + ((u >> 16) & 1u)) >> 16;  // RNE
    return (short)u;
}
__device__ __forceinline__ float bf2f(short s) {
    unsigned u = ((unsigned)(unsigned short)s) << 16;
    return __builtin_bit_cast(float, u);
}

// ---------------------------------------------------------------------------
// Kernel M: dist (int32 0/1, 268 MB) -> 1-bit adjacency mask (8 MB).
// Pure streaming: 128 B contiguous read + 4 B write per thread. ONLY reader
// of dist. Word w covers row i = w/256, j in [(w%256)*32, +32); bit = j%32.
// ---------------------------------------------------------------------------
__global__ __launch_bounds__(256, 8)
void mask_kernel(const int* __restrict__ dist, unsigned* __restrict__ mask) {
    size_t w = (size_t)blockIdx.x * 256 + threadIdx.x;   // 8192*256 words
    const int* p = dist + w * 32;
    unsigned b = 0;
    #pragma unroll
    for (int u = 0; u < 8; ++u) {
        i32x4 v = *(const i32x4*)(p + u * 4);
        #pragma unroll
        for (int e = 0; e < 4; ++e) b |= (v[e] > 0 ? 1u : 0u) << (u * 4 + e);
    }
    mask[w] = b;
}

// ---------------------------------------------------------------------------
// Kernel 0: split W [512][128] fp32 -> bf16 hi/lo in fragment-blocked layout:
// idx(col,k) = (k>>5)*(128*32) + col*32 + (k&31)
// ---------------------------------------------------------------------------
__global__ void split_w_kernel(const float* __restrict__ W,
                               short* __restrict__ WThi, short* __restrict__ WTlo) {
    int idx = blockIdx.x * 256 + threadIdx.x;       // 512*128 = 65536
    int k = idx >> 7, col = idx & 127;
    float x = W[idx];                               // row-major [k][col]
    short hi = f2bf(x);
    short lo = f2bf(x - bf2f(hi));
    size_t a = (size_t)(k >> 5) * (128 * 32) + (size_t)col * 32 + (k & 31);
    WThi[a] = hi;
    WTlo[a] = lo;
}

// ---------------------------------------------------------------------------
// Kernel 1: Wh = h@W via split-bf16 MFMA (3 products). Writes Wh1/Wh2 (fp32)
// and WhT bf16 fragment-blocked [(j>>5)][col][j&31].
// 512 blocks x 256 threads, 16 rows/block.
// ---------------------------------------------------------------------------
#define WH_ROWS 16
#define WH_STR 520   // 512 + 8 shorts pad: frag reads land 2-way (free)

__global__ __launch_bounds__(256, 2)
void wh_kernel(const float* __restrict__ h, const short* __restrict__ WThi,
               const short* __restrict__ WTlo, const float* __restrict__ a,
               short* __restrict__ WhT, float* __restrict__ Wh1,
               float* __restrict__ Wh2) {
    __shared__ __align__(16) short Ahi[WH_ROWS][WH_STR];
    __shared__ __align__(16) short Alo[WH_ROWS][WH_STR];
    __shared__ __align__(16) float whs[WH_ROWS][OUT_F + 4];

    const int t = threadIdx.x;
    const int r0 = blockIdx.x * WH_ROWS;

    {   // stage h tile [16][512] as bf16 hi/lo (coalesced 32B/lane reads)
        int row = t >> 4, c4 = t & 15;
        const float* hrow = h + (size_t)(r0 + row) * IN_F;
        #pragma unroll
        for (int jj = 0; jj < 4; ++jj) {
            int k0 = c4 * 8 + jj * 128;
            f32x4 x0 = *(const f32x4*)(hrow + k0);
            f32x4 x1 = *(const f32x4*)(hrow + k0 + 4);
            s16x8 hi, lo;
            #pragma unroll
            for (int e = 0; e < 4; ++e) {
                short h0 = f2bf(x0[e]); hi[e] = h0; lo[e] = f2bf(x0[e] - bf2f(h0));
                short h1 = f2bf(x1[e]); hi[4 + e] = h1; lo[4 + e] = f2bf(x1[e] - bf2f(h1));
            }
            *(s16x8*)&Ahi[row][k0] = hi;
            *(s16x8*)&Alo[row][k0] = lo;
        }
    }
    __syncthreads();

    const int lane = t & 63, w = t >> 6;
    const int q = lane >> 4, ln16 = lane & 15;
    f32x4 acc[2] = {};
    #pragma unroll
    for (int kc = 0; kc < IN_F / 32; ++kc) {
        s16x8 ahi = *(const s16x8*)&Ahi[ln16][kc * 32 + q * 8];
        s16x8 alo = *(const s16x8*)&Alo[ln16][kc * 32 + q * 8];
        #pragma unroll
        for (int nt = 0; nt < 2; ++nt) {
            int col = w * 32 + nt * 16 + ln16;
            size_t boff = (size_t)kc * 4096 + (size_t)col * 32 + q * 8;
            s16x8 bhi = *(const s16x8*)(WThi + boff);
            s16x8 blo = *(const s16x8*)(WTlo + boff);
            acc[nt] = __builtin_amdgcn_mfma_f32_16x16x32_bf16(ahi, bhi, acc[nt], 0, 0, 0);
            acc[nt] = __builtin_amdgcn_mfma_f32_16x16x32_bf16(ahi, blo, acc[nt], 0, 0, 0);
            acc[nt] = __builtin_amdgcn_mfma_f32_16x16x32_bf16(alo, bhi, acc[nt], 0, 0, 0);
        }
    }
    #pragma unroll
    for (int nt = 0; nt < 2; ++nt)
        #pragma unroll
        for (int reg = 0; reg < 4; ++reg)
            whs[q * 4 + reg][w * 32 + nt * 16 + ln16] = acc[nt][reg];
    __syncthreads();

    // Wh1/Wh2: 16 rows, 8 threads per row
    if (t < 128) {
        int r = t >> 3, s = t & 7;
        float s1 = 0.f, s2 = 0.f;
        #pragma unroll
        for (int cc = 0; cc < 16; ++cc) {
            int c = s * 16 + cc;
            float v = whs[r][c];
            s1 = fmaf(v, a[c], s1);
            s2 = fmaf(v, a[OUT_F + c], s2);
        }
        s1 += __shfl_xor(s1, 1); s1 += __shfl_xor(s1, 2); s1 += __shfl_xor(s1, 4);
        s2 += __shfl_xor(s2, 1); s2 += __shfl_xor(s2, 2); s2 += __shfl_xor(s2, 4);
        if (s == 0) { Wh1[r0 + r] = s1; Wh2[r0 + r] = s2; }
    }

    // WhT bf16, fragment-blocked: idx = (j>>5)*4096 + col*32 + (j&31)
    {
        int c = t >> 1, h8 = t & 1;
        s16x8 pack;
        #pragma unroll
        for (int rr = 0; rr < 8; ++rr) pack[rr] = f2bf(whs[h8 * 8 + rr][c]);
        size_t addr = (size_t)(r0 >> 5) * 4096 + (size_t)c * 32 + (r0 & 16) + h8 * 8;
        *(s16x8*)(WhT + addr) = pack;
    }
}

// ---------------------------------------------------------------------------
// Kernel 2 (v5): barrier-free (1 staging barrier) attention with ZERO cold
// loads in the hot loop:
//  - per-lane mask bytes for the whole j-span preloaded into 8 dwords (regs)
//  - Wh2 j-span staged once to LDS (4 KB, broadcast reads, conflict-free)
//  - WhT B-frags are the only in-loop global loads (same-XCD L2-hot: sp is
//    mapped to blockIdx%8 so all blocks sharing a j-span share an XCD L2)
//  - kc-loop fully unrolled -> all mb[] indexing static (no scratch), and
//    the scheduler can hoist B-frag loads many iterations ahead.
// grid = 128*SPLIT blocks (sp = blk&7), 256 threads, 64 rows/block.
// ---------------------------------------------------------------------------
#define BM2 64
#define SPLIT 8
#define NKC (N / (32 * SPLIT))   // 32
#define JSPAN (N / SPLIT)        // 1024

__global__ __launch_bounds__(256, 4)
void attn_kernel(const unsigned* __restrict__ mask, const short* __restrict__ WhT,
                 const float* __restrict__ Wh1v, const float* __restrict__ Wh2v,
                 float* __restrict__ acc_part, float* __restrict__ l_part) {
    __shared__ __align__(16) float wh2s[JSPAN];   // 4 KB

    const int t = threadIdx.x;
    const int sp = blockIdx.x & 7;        // same sp -> same XCD (round-robin)
    const int it = blockIdx.x >> 3;       // 128 i-tiles
    const int i0 = it * BM2;
    const int w = t >> 6, lane = t & 63;
    const int q = lane >> 4, ln16 = lane & 15;
    const int row = i0 + w * 16 + ln16;
    const int j0 = sp * JSPAN;

    // stage Wh2 span to LDS (coalesced 16 B/lane)
    *(f32x4*)&wh2s[t * 4] = *(const f32x4*)(Wh2v + j0 + t * 4);

    // per-lane mask bytes: q-byte of each of the 32 span words -> 8 dwords
    const unsigned* __restrict__ mp = mask + (size_t)row * (N / 32) + (j0 >> 5);
    unsigned mb[8];
    #pragma unroll
    for (int u = 0; u < 8; ++u) {
        i32x4 m = *(const i32x4*)(mp + u * 4);
        unsigned b0 = ((unsigned)m[0] >> (q * 8)) & 255u;
        unsigned b1 = ((unsigned)m[1] >> (q * 8)) & 255u;
        unsigned b2 = ((unsigned)m[2] >> (q * 8)) & 255u;
        unsigned b3 = ((unsigned)m[3] >> (q * 8)) & 255u;
        mb[u] = b0 | (b1 << 8) | (b2 << 16) | (b3 << 24);
    }

    const float wh1 = Wh1v[row];
    const short* __restrict__ wb0 =
        WhT + ((size_t)(j0 >> 5)) * 4096 + ln16 * 32 + q * 8;

    f32x4 acc[8] = {};
    float l_acc = 0.f;

    __syncthreads();   // wh2s ready; only barrier in the kernel

    #pragma unroll
    for (int kc = 0; kc < NKC; ++kc) {
        const unsigned byte = (mb[kc >> 2] >> ((kc & 3) * 8)) & 255u;
        const float* wsrc = &wh2s[kc * 32 + q * 8];
        f32x4 wA = *(const f32x4*)(wsrc);
        f32x4 wB = *(const f32x4*)(wsrc + 4);
        s16x8 af;
        #pragma unroll
        for (int e = 0; e < 4; ++e) {
            float sv = wh1 + wA[e];
            float lr = fmaxf(sv, ALPHA * sv);
            float pv = (byte & (1u << e)) ? __expf(lr) : 0.f;
            l_acc += pv;
            af[e] = f2bf(pv);
        }
        #pragma unroll
        for (int e = 0; e < 4; ++e) {
            float sv = wh1 + wB[e];
            float lr = fmaxf(sv, ALPHA * sv);
            float pv = (byte & (1u << (4 + e))) ? __expf(lr) : 0.f;
            l_acc += pv;
            af[4 + e] = f2bf(pv);
        }
        const short* wb = wb0 + (size_t)kc * 4096;
        #pragma unroll
        for (int nt = 0; nt < 8; ++nt) {
            s16x8 b = *(const s16x8*)(wb + nt * 512);   // col=nt*16+ln16
            acc[nt] = __builtin_amdgcn_mfma_f32_16x16x32_bf16(af, b, acc[nt], 0, 0, 0);
        }
    }

    // row sums: reduce the q-partials of each row
    l_acc += __shfl_xor(l_acc, 16);
    l_acc += __shfl_xor(l_acc, 32);
    if (lane < 16) l_part[(size_t)sp * N + row] = l_acc;

    // C/D: col = nt*16+ln16, row-within-16 = q*4+reg
    float* ap = acc_part + (size_t)sp * N * OUT_F + (size_t)(i0 + w * 16) * OUT_F;
    #pragma unroll
    for (int reg = 0; reg < 4; ++reg) {
        int rr = q * 4 + reg;
        #pragma unroll
        for (int nt = 0; nt < 8; ++nt)
            ap[(size_t)rr * OUT_F + nt * 16 + ln16] = acc[nt][reg];
    }
}

// ---------------------------------------------------------------------------
// Kernel 3: reduce partials, softmax-divide, elu, classifier.
// 512 blocks x 256 threads, 16 rows/block.
// ---------------------------------------------------------------------------
__global__ __launch_bounds__(256, 4)
void reduce_kernel(const float* __restrict__ acc_part, const float* __restrict__ l_part,
                   const float* __restrict__ Wc, const float* __restrict__ bcv,
                   float* __restrict__ out, int split) {
    __shared__ __align__(16) float hu[16][OUT_F + 4];
    const int t = threadIdx.x;
    const int i0 = blockIdx.x * 16;
    const int row = t >> 4, cg = t & 15;

    f32x4 v0 = {0.f, 0.f, 0.f, 0.f}, v1 = {0.f, 0.f, 0.f, 0.f};
    float l = 0.f;
    for (int s = 0; s < split; ++s) {
        const float* ap = acc_part + (size_t)s * N * OUT_F + (size_t)(i0 + row) * OUT_F + cg * 8;
        v0 += *(const f32x4*)ap;
        v1 += *(const f32x4*)(ap + 4);
        l += l_part[(size_t)s * N + i0 + row];
    }
    float inv = 1.f / l;
    #pragma unroll
    for (int e = 0; e < 4; ++e) {
        float x0 = v0[e] * inv; x0 = x0 > 0.f ? x0 : (__expf(x0) - 1.f);
        float x1 = v1[e] * inv; x1 = x1 > 0.f ? x1 : (__expf(x1) - 1.f);
        hu[row][cg * 8 + e] = x0;
        hu[row][cg * 8 + 4 + e] = x1;
    }
    __syncthreads();

    if (t < 16 * NCLS) {
        int rr = t / NCLS, cls = t - rr * NCLS;
        const f32x4* hurow = (const f32x4*)&hu[rr][0];
        const f32x4* wcrow = (const f32x4*)(Wc + cls * OUT_F);
        float sum = bcv[cls];
        #pragma unroll 8
        for (int c4 = 0; c4 < OUT_F / 4; ++c4) {
            f32x4 hv = hurow[c4];
            f32x4 wv = wcrow[c4];
            sum += hv[0] * wv[0] + hv[1] * wv[1] + hv[2] * wv[2] + hv[3] * wv[3];
        }
        out[(size_t)(i0 + rr) * NCLS + cls] = sum;
    }
}

// ---------------------------------------------------------------------------
extern "C" void kernel_launch(void* const* d_in, const int* in_sizes, int n_in,
                              void* d_out, int out_size, void* d_ws, size_t ws_size,
                              hipStream_t stream) {
    const float* h    = (const float*)d_in[0];
    const int*   dist = (const int*)d_in[1];
    const float* W    = (const float*)d_in[2];
    const float* a    = (const float*)d_in[3];
    const float* Wc   = (const float*)d_in[4];
    const float* bc   = (const float*)d_in[5];
    float* out = (float*)d_out;

    char* ws = (char*)d_ws;
    size_t off = 0;
    short* WhT  = (short*)(ws + off); off += (size_t)OUT_F * N * 2;     // 2 MB
    short* WThi = (short*)(ws + off); off += (size_t)IN_F * OUT_F * 2;  // 128 KB
    short* WTlo = (short*)(ws + off); off += (size_t)IN_F * OUT_F * 2;  // 128 KB
    float* Wh1  = (float*)(ws + off); off += (size_t)N * 4;
    float* Wh2  = (float*)(ws + off); off += (size_t)N * 4;
    unsigned* mask = (unsigned*)(ws + off); off += (size_t)N * (N / 32) * 4; // 8 MB

    float* acc_part = (float*)(ws + off); off += (size_t)SPLIT * N * OUT_F * 4; // 32 MB
    float* l_part   = (float*)(ws + off);

    hipLaunchKernelGGL(mask_kernel, dim3(N * (N / 32) / 256), dim3(256), 0, stream,
                       dist, mask);
    hipLaunchKernelGGL(split_w_kernel, dim3(256), dim3(256), 0, stream, W, WThi, WTlo);
    hipLaunchKernelGGL(wh_kernel, dim3(N / WH_ROWS), dim3(256), 0, stream,
                       h, WThi, WTlo, a, WhT, Wh1, Wh2);
    hipLaunchKernelGGL(attn_kernel, dim3(128 * SPLIT), dim3(256), 0, stream,
                       mask, WhT, Wh1, Wh2, acc_part, l_part);
    hipLaunchKernelGGL(reduce_kernel, dim3(N / 16), dim3(256), 0, stream,
                       acc_part, l_part, Wc, bc, out, SPLIT);
}

// Round 6
// 443.447 us; speedup vs baseline: 1.0994x; 1.0666x over previous
//
#include <hip/hip_runtime.h>
#include <stdint.h>

#define N 8192
#define IN_F 512
#define OUT_F 128
#define NCLS 10
#define ALPHA 0.2f

typedef float f32x4 __attribute__((ext_vector_type(4)));
typedef int   i32x4 __attribute__((ext_vector_type(4)));
typedef short s16x4 __attribute__((ext_vector_type(4)));
typedef short s16x8 __attribute__((ext_vector_type(8)));

__device__ __forceinline__ short f2bf(float x) {
    unsigned u = __builtin_bit_cast(unsigned, x);
    u = (u + 0x7FFFu + ((u >> 16) & 1u)) >> 16;  // RNE
    return (short)u;
}
__device__ __forceinline__ float bf2f(short s) {
    unsigned u = ((unsigned)(unsigned short)s) << 16;
    return __builtin_bit_cast(float, u);
}

// ---------------------------------------------------------------------------
// Kernel M: dist (int32 0/1, 268 MB) -> 1-bit adjacency mask (8 MB).
// Pure streaming: 128 B contiguous read + 4 B write per thread. ONLY reader
// of dist. Word w covers row i = w/256, j in [(w%256)*32, +32); bit = j%32.
// ---------------------------------------------------------------------------
__global__ __launch_bounds__(256, 8)
void mask_kernel(const int* __restrict__ dist, unsigned* __restrict__ mask) {
    size_t w = (size_t)blockIdx.x * 256 + threadIdx.x;   // 8192*256 words
    const int* p = dist + w * 32;
    unsigned b = 0;
    #pragma unroll
    for (int u = 0; u < 8; ++u) {
        i32x4 v = *(const i32x4*)(p + u * 4);
        #pragma unroll
        for (int e = 0; e < 4; ++e) b |= (v[e] > 0 ? 1u : 0u) << (u * 4 + e);
    }
    mask[w] = b;
}

// ---------------------------------------------------------------------------
// Kernel 0: split W [512][128] fp32 -> bf16 hi/lo in fragment-blocked layout:
// idx(col,k) = (k>>5)*(128*32) + col*32 + (k&31)
// ---------------------------------------------------------------------------
__global__ void split_w_kernel(const float* __restrict__ W,
                               short* __restrict__ WThi, short* __restrict__ WTlo) {
    int idx = blockIdx.x * 256 + threadIdx.x;       // 512*128 = 65536
    int k = idx >> 7, col = idx & 127;
    float x = W[idx];                               // row-major [k][col]
    short hi = f2bf(x);
    short lo = f2bf(x - bf2f(hi));
    size_t a = (size_t)(k >> 5) * (128 * 32) + (size_t)col * 32 + (k & 31);
    WThi[a] = hi;
    WTlo[a] = lo;
}

// ---------------------------------------------------------------------------
// Kernel 1: Wh = h@W via split-bf16 MFMA (3 products). Writes Wh1/Wh2 (fp32)
// and WhT bf16 fragment-blocked [(j>>5)][col][j&31].
// 512 blocks x 256 threads, 16 rows/block.
// ---------------------------------------------------------------------------
#define WH_ROWS 16
#define WH_STR 520   // 512 + 8 shorts pad: frag reads land 2-way (free)

__global__ __launch_bounds__(256, 2)
void wh_kernel(const float* __restrict__ h, const short* __restrict__ WThi,
               const short* __restrict__ WTlo, const float* __restrict__ a,
               short* __restrict__ WhT, float* __restrict__ Wh1,
               float* __restrict__ Wh2) {
    __shared__ __align__(16) short Ahi[WH_ROWS][WH_STR];
    __shared__ __align__(16) short Alo[WH_ROWS][WH_STR];
    __shared__ __align__(16) float whs[WH_ROWS][OUT_F + 4];

    const int t = threadIdx.x;
    const int r0 = blockIdx.x * WH_ROWS;

    {   // stage h tile [16][512] as bf16 hi/lo (coalesced 32B/lane reads)
        int row = t >> 4, c4 = t & 15;
        const float* hrow = h + (size_t)(r0 + row) * IN_F;
        #pragma unroll
        for (int jj = 0; jj < 4; ++jj) {
            int k0 = c4 * 8 + jj * 128;
            f32x4 x0 = *(const f32x4*)(hrow + k0);
            f32x4 x1 = *(const f32x4*)(hrow + k0 + 4);
            s16x8 hi, lo;
            #pragma unroll
            for (int e = 0; e < 4; ++e) {
                short h0 = f2bf(x0[e]); hi[e] = h0; lo[e] = f2bf(x0[e] - bf2f(h0));
                short h1 = f2bf(x1[e]); hi[4 + e] = h1; lo[4 + e] = f2bf(x1[e] - bf2f(h1));
            }
            *(s16x8*)&Ahi[row][k0] = hi;
            *(s16x8*)&Alo[row][k0] = lo;
        }
    }
    __syncthreads();

    const int lane = t & 63, w = t >> 6;
    const int q = lane >> 4, ln16 = lane & 15;
    f32x4 acc[2] = {};
    #pragma unroll
    for (int kc = 0; kc < IN_F / 32; ++kc) {
        s16x8 ahi = *(const s16x8*)&Ahi[ln16][kc * 32 + q * 8];
        s16x8 alo = *(const s16x8*)&Alo[ln16][kc * 32 + q * 8];
        #pragma unroll
        for (int nt = 0; nt < 2; ++nt) {
            int col = w * 32 + nt * 16 + ln16;
            size_t boff = (size_t)kc * 4096 + (size_t)col * 32 + q * 8;
            s16x8 bhi = *(const s16x8*)(WThi + boff);
            s16x8 blo = *(const s16x8*)(WTlo + boff);
            acc[nt] = __builtin_amdgcn_mfma_f32_16x16x32_bf16(ahi, bhi, acc[nt], 0, 0, 0);
            acc[nt] = __builtin_amdgcn_mfma_f32_16x16x32_bf16(ahi, blo, acc[nt], 0, 0, 0);
            acc[nt] = __builtin_amdgcn_mfma_f32_16x16x32_bf16(alo, bhi, acc[nt], 0, 0, 0);
        }
    }
    #pragma unroll
    for (int nt = 0; nt < 2; ++nt)
        #pragma unroll
        for (int reg = 0; reg < 4; ++reg)
            whs[q * 4 + reg][w * 32 + nt * 16 + ln16] = acc[nt][reg];
    __syncthreads();

    // Wh1/Wh2: 16 rows, 8 threads per row
    if (t < 128) {
        int r = t >> 3, s = t & 7;
        float s1 = 0.f, s2 = 0.f;
        #pragma unroll
        for (int cc = 0; cc < 16; ++cc) {
            int c = s * 16 + cc;
            float v = whs[r][c];
            s1 = fmaf(v, a[c], s1);
            s2 = fmaf(v, a[OUT_F + c], s2);
        }
        s1 += __shfl_xor(s1, 1); s1 += __shfl_xor(s1, 2); s1 += __shfl_xor(s1, 4);
        s2 += __shfl_xor(s2, 1); s2 += __shfl_xor(s2, 2); s2 += __shfl_xor(s2, 4);
        if (s == 0) { Wh1[r0 + r] = s1; Wh2[r0 + r] = s2; }
    }

    // WhT bf16, fragment-blocked: idx = (j>>5)*4096 + col*32 + (j&31)
    {
        int c = t >> 1, h8 = t & 1;
        s16x8 pack;
        #pragma unroll
        for (int rr = 0; rr < 8; ++rr) pack[rr] = f2bf(whs[h8 * 8 + rr][c]);
        size_t addr = (size_t)(r0 >> 5) * 4096 + (size_t)c * 32 + (r0 & 16) + h8 * 8;
        *(s16x8*)(WhT + addr) = pack;
    }
}

// ---------------------------------------------------------------------------
// Kernel 2 (v6): r2's LDS-P attention with occupancy + staging fixes.
//  - BK 256->128: As[2][32][136] = 17.4 KB; + wh2s 8 KB => 25.4 KB/block
//    -> 6 blocks/CU (was 4). launch_bounds(256,6) (<=85 VGPR, ~65 used).
//  - Wh2 j-span staged to LDS once (coalesced, broadcast reads, no per-tile
//    global Wh2 traffic).
//  - mask: one i32x4 prefetch per tile (4 words = 128 j).
// grid = 256 i-tiles * SPLIT, 256 threads (4 waves), 32 rows/block.
// ---------------------------------------------------------------------------
#define BM 32
#define BK 128
#define ASTR (BK + 8)            // 136 shorts
#define SPLIT 4
#define NIT (N / (BK * SPLIT))   // 16
#define JSPAN (N / SPLIT)        // 2048

__global__ __launch_bounds__(256, 6)
void attn_kernel(const unsigned* __restrict__ mask, const short* __restrict__ WhT,
                 const float* __restrict__ Wh1v, const float* __restrict__ Wh2v,
                 float* __restrict__ acc_part, float* __restrict__ l_part) {
    __shared__ __align__(16) short As[2][BM][ASTR];   // 17408 B
    __shared__ __align__(16) float wh2s[JSPAN];       // 8192 B

    const int t = threadIdx.x;
    const int it = blockIdx.x & 255;
    const int sp = blockIdx.x >> 8;
    const int i0 = it * BM;
    const int r = t >> 3, s = t & 7;       // p-phase: row r, j-slice s
    const int lane = t & 63, w = t >> 6;   // mfma-phase
    const int q = lane >> 4, ln16 = lane & 15;
    const int j0 = sp * JSPAN;
    const int sh = s * 4;

    {   // stage Wh2 span once (32 B/lane coalesced)
        f32x4 a0 = *(const f32x4*)(Wh2v + j0 + t * 8);
        f32x4 a1 = *(const f32x4*)(Wh2v + j0 + t * 8 + 4);
        *(f32x4*)&wh2s[t * 8] = a0;
        *(f32x4*)&wh2s[t * 8 + 4] = a1;
    }

    const unsigned* __restrict__ mrow = mask + (size_t)(i0 + r) * (N / 32) + (j0 >> 5);
    const float wh1 = Wh1v[i0 + r];
    float l_acc = 0.f;
    f32x4 acc[2][2] = {};

    i32x4 m = *(const i32x4*)mrow;         // 4 words = first tile's 128 j
    __syncthreads();                        // wh2s ready

    for (int kt = 0; kt < NIT; ++kt) {
        const int jb = kt * BK;
        i32x4 mn = m;
        if (kt + 1 < NIT) mn = *(const i32x4*)(mrow + (kt + 1) * 4);
        short* arow = &As[kt & 1][r][0];
        #pragma unroll
        for (int u = 0; u < 4; ++u) {
            f32x4 w2 = *(const f32x4*)&wh2s[jb + u * 32 + sh];
            unsigned nib = ((unsigned)m[u] >> sh) & 15u;
            s16x4 pk;
            #pragma unroll
            for (int e = 0; e < 4; ++e) {
                float sv = wh1 + w2[e];
                float lr = fmaxf(sv, ALPHA * sv);
                float pv = (nib & (1u << e)) ? __expf(lr) : 0.f;
                l_acc += pv;
                pk[e] = f2bf(pv);
            }
            *(s16x4*)(arow + u * 32 + sh) = pk;
        }
        __syncthreads();
        const short* ab = &As[kt & 1][0][0];
        const short* bbase = WhT + (size_t)(j0 + jb) * 128;   // blocked layout
        #pragma unroll
        for (int kc = 0; kc < BK / 32; ++kc) {
            s16x8 a0 = *(const s16x8*)(ab + ln16 * ASTR + kc * 32 + q * 8);
            s16x8 a1 = *(const s16x8*)(ab + (16 + ln16) * ASTR + kc * 32 + q * 8);
            #pragma unroll
            for (int nt = 0; nt < 2; ++nt) {
                int col = w * 32 + nt * 16 + ln16;
                s16x8 b = *(const s16x8*)(bbase + (size_t)kc * 4096 + col * 32 + q * 8);
                acc[0][nt] = __builtin_amdgcn_mfma_f32_16x16x32_bf16(a0, b, acc[0][nt], 0, 0, 0);
                acc[1][nt] = __builtin_amdgcn_mfma_f32_16x16x32_bf16(a1, b, acc[1][nt], 0, 0, 0);
            }
        }
        m = mn;
    }

    // partial row sums
    l_acc += __shfl_xor(l_acc, 1);
    l_acc += __shfl_xor(l_acc, 2);
    l_acc += __shfl_xor(l_acc, 4);
    if (s == 0) l_part[(size_t)sp * N + i0 + r] = l_acc;

    // partial acc (C/D: col=lane&15, row=q*4+reg)
    float* ap = acc_part + (size_t)sp * N * OUT_F + (size_t)i0 * OUT_F;
    #pragma unroll
    for (int mt = 0; mt < 2; ++mt)
        #pragma unroll
        for (int reg = 0; reg < 4; ++reg) {
            int row = mt * 16 + q * 4 + reg;
            #pragma unroll
            for (int nt = 0; nt < 2; ++nt)
                ap[(size_t)row * OUT_F + w * 32 + nt * 16 + ln16] = acc[mt][nt][reg];
        }
}

// ---------------------------------------------------------------------------
// Kernel 3: reduce partials, softmax-divide, elu, classifier.
// 512 blocks x 256 threads, 16 rows/block.
// ---------------------------------------------------------------------------
__global__ __launch_bounds__(256, 4)
void reduce_kernel(const float* __restrict__ acc_part, const float* __restrict__ l_part,
                   const float* __restrict__ Wc, const float* __restrict__ bcv,
                   float* __restrict__ out, int split) {
    __shared__ __align__(16) float hu[16][OUT_F + 4];
    const int t = threadIdx.x;
    const int i0 = blockIdx.x * 16;
    const int row = t >> 4, cg = t & 15;

    f32x4 v0 = {0.f, 0.f, 0.f, 0.f}, v1 = {0.f, 0.f, 0.f, 0.f};
    float l = 0.f;
    for (int s = 0; s < split; ++s) {
        const float* ap = acc_part + (size_t)s * N * OUT_F + (size_t)(i0 + row) * OUT_F + cg * 8;
        v0 += *(const f32x4*)ap;
        v1 += *(const f32x4*)(ap + 4);
        l += l_part[(size_t)s * N + i0 + row];
    }
    float inv = 1.f / l;
    #pragma unroll
    for (int e = 0; e < 4; ++e) {
        float x0 = v0[e] * inv; x0 = x0 > 0.f ? x0 : (__expf(x0) - 1.f);
        float x1 = v1[e] * inv; x1 = x1 > 0.f ? x1 : (__expf(x1) - 1.f);
        hu[row][cg * 8 + e] = x0;
        hu[row][cg * 8 + 4 + e] = x1;
    }
    __syncthreads();

    if (t < 16 * NCLS) {
        int rr = t / NCLS, cls = t - rr * NCLS;
        const f32x4* hurow = (const f32x4*)&hu[rr][0];
        const f32x4* wcrow = (const f32x4*)(Wc + cls * OUT_F);
        float sum = bcv[cls];
        #pragma unroll 8
        for (int c4 = 0; c4 < OUT_F / 4; ++c4) {
            f32x4 hv = hurow[c4];
            f32x4 wv = wcrow[c4];
            sum += hv[0] * wv[0] + hv[1] * wv[1] + hv[2] * wv[2] + hv[3] * wv[3];
        }
        out[(size_t)(i0 + rr) * NCLS + cls] = sum;
    }
}

// ---------------------------------------------------------------------------
extern "C" void kernel_launch(void* const* d_in, const int* in_sizes, int n_in,
                              void* d_out, int out_size, void* d_ws, size_t ws_size,
                              hipStream_t stream) {
    const float* h    = (const float*)d_in[0];
    const int*   dist = (const int*)d_in[1];
    const float* W    = (const float*)d_in[2];
    const float* a    = (const float*)d_in[3];
    const float* Wc   = (const float*)d_in[4];
    const float* bc   = (const float*)d_in[5];
    float* out = (float*)d_out;

    char* ws = (char*)d_ws;
    size_t off = 0;
    short* WhT  = (short*)(ws + off); off += (size_t)OUT_F * N * 2;     // 2 MB
    short* WThi = (short*)(ws + off); off += (size_t)IN_F * OUT_F * 2;  // 128 KB
    short* WTlo = (short*)(ws + off); off += (size_t)IN_F * OUT_F * 2;  // 128 KB
    float* Wh1  = (float*)(ws + off); off += (size_t)N * 4;
    float* Wh2  = (float*)(ws + off); off += (size_t)N * 4;
    unsigned* mask = (unsigned*)(ws + off); off += (size_t)N * (N / 32) * 4; // 8 MB

    float* acc_part = (float*)(ws + off); off += (size_t)SPLIT * N * OUT_F * 4; // 16 MB
    float* l_part   = (float*)(ws + off);

    hipLaunchKernelGGL(mask_kernel, dim3(N * (N / 32) / 256), dim3(256), 0, stream,
                       dist, mask);
    hipLaunchKernelGGL(split_w_kernel, dim3(256), dim3(256), 0, stream, W, WThi, WTlo);
    hipLaunchKernelGGL(wh_kernel, dim3(N / WH_ROWS), dim3(256), 0, stream,
                       h, WThi, WTlo, a, WhT, Wh1, Wh2);
    hipLaunchKernelGGL(attn_kernel, dim3(256 * SPLIT), dim3(256), 0, stream,
                       mask, WhT, Wh1, Wh2, acc_part, l_part);
    hipLaunchKernelGGL(reduce_kernel, dim3(N / 16), dim3(256), 0, stream,
                       acc_part, l_part, Wc, bc, out, SPLIT);
}